// Round 1
// 836.337 us; speedup vs baseline: 1.4359x; 1.4359x over previous
//
#include <hip/hip_runtime.h>

#define NN 100000
#define NE 1000000

// d_out layout in FLOAT32 elements, concatenated reference-return order
#define OUT_EA  6400000ull    // edge_attr echo
#define OUT_U   70400000ull   // u echo
#define OUT_EI  70401024ull   // edge_index echo (ints as floats)

// Broadcast a float from a compile-time lane via v_readlane (VALU pipe, SGPR dest).
__device__ __forceinline__ float bcastf(float v, int srclane) {
    return __int_as_float(__builtin_amdgcn_readlane(__float_as_int(v), srclane));
}

// ---------------------------------------------------------------------------
// proj: one of {k,q,v} per blockIdx.y:  o = x@W^T + b
// A rows live in registers (coalesced float4 direct from global, no LDS tile,
// no broadcast ds_reads). W transposed in LDS (WT[k][d], pad 65) so the
// per-lane w[d=lane][k] read is a conflict-free b32. a[m][k] broadcast via
// v_readlane (lane = (m&3)*16 + (k>>2), component k&3) — compile-time lanes.
// ---------------------------------------------------------------------------
__global__ __launch_bounds__(256, 4) void proj_kernel(
    const float* __restrict__ x,
    const float* __restrict__ Wk, const float* __restrict__ bk,
    const float* __restrict__ Wq, const float* __restrict__ bq,
    const float* __restrict__ Wv, const float* __restrict__ bv,
    float* __restrict__ ko, float* __restrict__ qo, float* __restrict__ vo)
{
    __shared__ float WT[64 * 65];
    const int tid = threadIdx.x;
    const int lane = tid & 63, wave = tid >> 6;

    const float* W = blockIdx.y == 0 ? Wk : blockIdx.y == 1 ? Wq : Wv;
    const float* b = blockIdx.y == 0 ? bk : blockIdx.y == 1 ? bq : bv;
    float*       o = blockIdx.y == 0 ? ko : blockIdx.y == 1 ? qo : vo;

    for (int i = tid; i < 64 * 64; i += 256) {
        int d = i >> 6, k = i & 63;
        WT[k * 65 + d] = W[i];            // write banks (k+d)%32: conflict-free
    }
    __syncthreads();

    const float bias = b[lane];
    const int base = blockIdx.x * 32 + wave * 8;   // NN = 3125*32 exactly

    // 8 rows x 64 floats = 128 float4; lane l covers row base+(l>>4), cols (l&15)*4..+3
    const float4* src = (const float4*)(x + (size_t)base * 64);
    float4 A0 = src[lane];
    float4 A1 = src[64 + lane];

    float acc[8];
#pragma unroll
    for (int m = 0; m < 8; m++) acc[m] = bias;

#pragma unroll
    for (int k = 0; k < 64; k++) {
        float w = WT[k * 65 + lane];      // w[d=lane][k], conflict-free b32
        const int ls = k >> 2, c = k & 3;
#pragma unroll
        for (int m = 0; m < 8; m++) {
            float comp = (m < 4)
                ? (c == 0 ? A0.x : c == 1 ? A0.y : c == 2 ? A0.z : A0.w)
                : (c == 0 ? A1.x : c == 1 ? A1.y : c == 2 ? A1.z : A1.w);
            float a = bcastf(comp, (m & 3) * 16 + ls);
            acc[m] = fmaf(a, w, acc[m]);
        }
    }

#pragma unroll
    for (int m = 0; m < 8; m++)
        o[(size_t)(base + m) * 64 + lane] = acc[m];
}

// ---------------------------------------------------------------------------
// edge: e = edge_attr@We^T+be (registers, never materialized), gather k/q/v,
// gated message, atomic scatter into agg. Echo written from the same registers
// the GEMM consumes (ea read exactly once). No per-tile barriers.
// ---------------------------------------------------------------------------
__global__ __launch_bounds__(256, 4) void edge_kernel(
    const float* __restrict__ ea, const int* __restrict__ ei,
    const float* __restrict__ We, const float* __restrict__ be,
    const float* __restrict__ ko, const float* __restrict__ qo, const float* __restrict__ vo,
    float* __restrict__ agg, float* __restrict__ out)
{
    __shared__ float WT[64 * 65];
    const int tid = threadIdx.x;
    const int lane = tid & 63, wave = tid >> 6;

    for (int i = tid; i < 64 * 64; i += 256) {
        int d = i >> 6, k = i & 63;
        WT[k * 65 + d] = We[i];
    }
    __syncthreads();

    const float bias = be[lane];
    float* echo = out + OUT_EA;

    // per-wave chunks of 8 edges; NE = 1e6 is a multiple of 8, loads always full
    for (int base = blockIdx.x * 32 + wave * 8; base < NE; base += gridDim.x * 32) {
        const float4* src = (const float4*)(ea + (size_t)base * 64);
        float4 A0 = src[lane];            // rows base..base+3 (coalesced 1 KiB)
        float4 A1 = src[64 + lane];       // rows base+4..base+7
        float4* ech = (float4*)(echo + (size_t)base * 64);
        ech[lane] = A0;                   // identity echo from registers
        ech[64 + lane] = A1;

        float acc[8];
#pragma unroll
        for (int m = 0; m < 8; m++) acc[m] = bias;

#pragma unroll
        for (int k = 0; k < 64; k++) {
            float w = WT[k * 65 + lane];
            const int ls = k >> 2, c = k & 3;
#pragma unroll
            for (int m = 0; m < 8; m++) {
                float comp = (m < 4)
                    ? (c == 0 ? A0.x : c == 1 ? A0.y : c == 2 ? A0.z : A0.w)
                    : (c == 0 ? A1.x : c == 1 ? A1.y : c == 2 ? A1.z : A1.w);
                float a = bcastf(comp, (m & 3) * 16 + ls);
                acc[m] = fmaf(a, w, acc[m]);
            }
        }

#pragma unroll
        for (int m = 0; m < 8; m++) {
            int e = base + m;
            int s = ei[e];
            int t = ei[NE + e];
            float ev = acc[m];
            float kd = ko[(size_t)t * 64 + lane];
            float qj = qo[(size_t)s * 64 + lane];
            float vj = vo[(size_t)s * 64 + lane];
            float z = kd + qj + ev + ev;               // (k_i+e) + (q_j+e)
            float g = 1.0f / (1.0f + __expf(-z));
            atomicAdd(&agg[(size_t)t * 64 + lane], g * (vj + ev));
        }
    }
}

// ---------------------------------------------------------------------------
// final: out = relu(agg + x@Ws^T + bs)
// ---------------------------------------------------------------------------
__global__ __launch_bounds__(256, 4) void final_kernel(
    const float* __restrict__ x, const float* __restrict__ Ws, const float* __restrict__ bs,
    const float* __restrict__ agg, float* __restrict__ out)
{
    __shared__ float WT[64 * 65];
    const int tid = threadIdx.x;
    const int lane = tid & 63, wave = tid >> 6;

    for (int i = tid; i < 64 * 64; i += 256) {
        int d = i >> 6, k = i & 63;
        WT[k * 65 + d] = Ws[i];
    }
    __syncthreads();

    const float bias = bs[lane];
    const int base = blockIdx.x * 32 + wave * 8;

    const float4* src = (const float4*)(x + (size_t)base * 64);
    float4 A0 = src[lane];
    float4 A1 = src[64 + lane];

    float acc[8];
#pragma unroll
    for (int m = 0; m < 8; m++) acc[m] = bias;

#pragma unroll
    for (int k = 0; k < 64; k++) {
        float w = WT[k * 65 + lane];
        const int ls = k >> 2, c = k & 3;
#pragma unroll
        for (int m = 0; m < 8; m++) {
            float comp = (m < 4)
                ? (c == 0 ? A0.x : c == 1 ? A0.y : c == 2 ? A0.z : A0.w)
                : (c == 0 ? A1.x : c == 1 ? A1.y : c == 2 ? A1.z : A1.w);
            float a = bcastf(comp, (m & 3) * 16 + ls);
            acc[m] = fmaf(a, w, acc[m]);
        }
    }

#pragma unroll
    for (int m = 0; m < 8; m++) {
        int row = base + m;
        float r = acc[m] + agg[(size_t)row * 64 + lane];
        out[(size_t)row * 64 + lane] = r > 0.0f ? r : 0.0f;
    }
}

// ---------------------------------------------------------------------------
// echo u (1024 floats) and edge_index (2M ints -> floats)
// ---------------------------------------------------------------------------
__global__ __launch_bounds__(256) void echo_kernel(
    const float* __restrict__ u, const int* __restrict__ ei, float* __restrict__ out)
{
    int i = blockIdx.x * 256 + threadIdx.x;
    if (i < 1024) out[OUT_U + i] = u[i];
    if (i < 2000000) out[OUT_EI + i] = (float)ei[i];
}

extern "C" void kernel_launch(void* const* d_in, const int* in_sizes, int n_in,
                              void* d_out, int out_size, void* d_ws, size_t ws_size,
                              hipStream_t stream)
{
    const float* x  = (const float*)d_in[0];
    const int*   ei = (const int*)d_in[1];
    const float* ea = (const float*)d_in[2];
    const float* u  = (const float*)d_in[3];
    // d_in[4] = batch (unused by reference output)
    const float* Wk = (const float*)d_in[5];
    const float* bk = (const float*)d_in[6];
    const float* Wq = (const float*)d_in[7];
    const float* bq = (const float*)d_in[8];
    const float* Wv = (const float*)d_in[9];
    const float* bv = (const float*)d_in[10];
    const float* We = (const float*)d_in[11];
    const float* be = (const float*)d_in[12];
    const float* Ws = (const float*)d_in[13];
    const float* bs = (const float*)d_in[14];
    float* out = (float*)d_out;

    float* ws  = (float*)d_ws;
    float* ko  = ws;
    float* qo  = ws + 6400000;
    float* vo  = ws + 12800000;
    float* agg = ws + 19200000;

    hipMemsetAsync(agg, 0, (size_t)6400000 * 4, stream);
    proj_kernel <<<dim3(3125, 3), 256, 0, stream>>>(x, Wk, bk, Wq, bq, Wv, bv, ko, qo, vo);
    edge_kernel <<<2048, 256, 0, stream>>>(ea, ei, We, be, ko, qo, vo, agg, out);
    final_kernel<<<3125, 256, 0, stream>>>(x, Ws, bs, agg, out);
    echo_kernel <<<7813, 256, 0, stream>>>(u, ei, out);
}

// Round 2
// 805.586 us; speedup vs baseline: 1.4907x; 1.0382x over previous
//
#include <hip/hip_runtime.h>

#define NN 100000
#define NE 1000000

// d_out layout in FLOAT32 elements, concatenated reference-return order
#define OUT_EA  6400000ull    // edge_attr echo
#define OUT_U   70400000ull   // u echo
#define OUT_EI  70401024ull   // edge_index echo (ints as floats)

// Broadcast a float from a compile-time lane via v_readlane (VALU pipe, SGPR dest).
__device__ __forceinline__ float bcastf(float v, int srclane) {
    return __int_as_float(__builtin_amdgcn_readlane(__float_as_int(v), srclane));
}
__device__ __forceinline__ int rfl(int v) { return __builtin_amdgcn_readfirstlane(v); }

// ---------------------------------------------------------------------------
// proj: blockIdx.y in {0,1,2}: o = x@W^T + b  for {k,q,v}.  blockIdx.y==3:
// zero the agg buffer (replaces hipMemsetAsync -> one fewer dispatch).
// A rows in registers (coalesced float4), W transposed in LDS (pad 65),
// a[m][k] broadcast via v_readlane at compile-time lanes.
// ---------------------------------------------------------------------------
__global__ __launch_bounds__(256, 4) void proj_kernel(
    const float* __restrict__ x,
    const float* __restrict__ Wk, const float* __restrict__ bk,
    const float* __restrict__ Wq, const float* __restrict__ bq,
    const float* __restrict__ Wv, const float* __restrict__ bv,
    float* __restrict__ ko, float* __restrict__ qo, float* __restrict__ vo,
    float* __restrict__ agg)
{
    const int tid = threadIdx.x;

    if (blockIdx.y == 3) {               // zero agg: 6.4M floats = 1.6M float4
        const float4 z = make_float4(0.f, 0.f, 0.f, 0.f);
        for (int i = blockIdx.x * 256 + tid; i < 1600000; i += 800000)
            ((float4*)agg)[i] = z;
        return;
    }

    __shared__ float WT[64 * 65];
    const int lane = tid & 63, wave = tid >> 6;

    const float* W = blockIdx.y == 0 ? Wk : blockIdx.y == 1 ? Wq : Wv;
    const float* b = blockIdx.y == 0 ? bk : blockIdx.y == 1 ? bq : bv;
    float*       o = blockIdx.y == 0 ? ko : blockIdx.y == 1 ? qo : vo;

    for (int i = tid; i < 64 * 64; i += 256) {
        int d = i >> 6, k = i & 63;
        WT[k * 65 + d] = W[i];           // write banks (k+d)%32: conflict-free
    }
    __syncthreads();

    const float bias = b[lane];
    const int base = blockIdx.x * 32 + wave * 8;   // NN = 3125*32 exactly

    const float4* src = (const float4*)(x + (size_t)base * 64);
    float4 A0 = src[lane];
    float4 A1 = src[64 + lane];

    float acc[8];
#pragma unroll
    for (int m = 0; m < 8; m++) acc[m] = bias;

#pragma unroll
    for (int k = 0; k < 64; k++) {
        float w = WT[k * 65 + lane];     // w[d=lane][k], conflict-free b32
        const int ls = k >> 2, c = k & 3;
#pragma unroll
        for (int m = 0; m < 8; m++) {
            float comp = (m < 4)
                ? (c == 0 ? A0.x : c == 1 ? A0.y : c == 2 ? A0.z : A0.w)
                : (c == 0 ? A1.x : c == 1 ? A1.y : c == 2 ? A1.z : A1.w);
            float a = bcastf(comp, (m & 3) * 16 + ls);
            acc[m] = fmaf(a, w, acc[m]);
        }
    }

#pragma unroll
    for (int m = 0; m < 8; m++)
        o[(size_t)(base + m) * 64 + lane] = acc[m];
}

// ---------------------------------------------------------------------------
// edge: software-pipelined. Per iteration:
//   1) issue k/q/v gathers for CURRENT group (indices in SGPRs from prev iter)
//   2) prefetch NEXT group's ea rows + edge indices
//   3) echo current ea rows
//   4) register GEMM (e = ea@We^T+be) -- ~2k cycles, covers all VMEM latency
//   5) epilogue consumes gathers (now landed): gate + atomic scatter
// ---------------------------------------------------------------------------
__global__ __launch_bounds__(256, 4) void edge_kernel(
    const float* __restrict__ ea, const int* __restrict__ ei,
    const float* __restrict__ We, const float* __restrict__ be,
    const float* __restrict__ ko, const float* __restrict__ qo, const float* __restrict__ vo,
    float* __restrict__ agg, float* __restrict__ out)
{
    __shared__ float WT[64 * 65];
    const int tid = threadIdx.x;
    const int lane = tid & 63, wave = tid >> 6;

    for (int i = tid; i < 64 * 64; i += 256) {
        int d = i >> 6, k = i & 63;
        WT[k * 65 + d] = We[i];
    }
    __syncthreads();

    const float bias = be[lane];
    float* echo = out + OUT_EA;
    const int stride = gridDim.x * 32;

    int gb = rfl(blockIdx.x * 32 + wave * 8);   // wave-uniform SGPR group base
    if (gb >= NE) return;

    // ---- prologue: load first group's A rows + indices ----
    float4 A0, A1;
    int s[8], t[8];
    {
        const float4* src = (const float4*)(ea + (size_t)gb * 64);
        A0 = src[lane]; A1 = src[64 + lane];
        int4 sa = *(const int4*)(ei + gb);
        int4 sb = *(const int4*)(ei + gb + 4);
        int4 ta = *(const int4*)(ei + NE + gb);
        int4 tb = *(const int4*)(ei + NE + gb + 4);
        s[0]=rfl(sa.x); s[1]=rfl(sa.y); s[2]=rfl(sa.z); s[3]=rfl(sa.w);
        s[4]=rfl(sb.x); s[5]=rfl(sb.y); s[6]=rfl(sb.z); s[7]=rfl(sb.w);
        t[0]=rfl(ta.x); t[1]=rfl(ta.y); t[2]=rfl(ta.z); t[3]=rfl(ta.w);
        t[4]=rfl(tb.x); t[5]=rfl(tb.y); t[6]=rfl(tb.z); t[7]=rfl(tb.w);
    }

    while (true) {
        const int nb = gb + stride;
        const bool has_next = nb < NE;

        // (1) issue gathers for current group (consumed only after the GEMM)
        float kd[8], qj[8], vj[8];
#pragma unroll
        for (int m = 0; m < 8; m++) {
            kd[m] = ko[(size_t)t[m] * 64 + lane];
            qj[m] = qo[(size_t)s[m] * 64 + lane];
            vj[m] = vo[(size_t)s[m] * 64 + lane];
        }

        // (2) prefetch next group's A rows + indices
        float4 B0, B1;
        int ns[8], nt[8];
        if (has_next) {
            const float4* nsrc = (const float4*)(ea + (size_t)nb * 64);
            B0 = nsrc[lane]; B1 = nsrc[64 + lane];
            int4 sa = *(const int4*)(ei + nb);
            int4 sb = *(const int4*)(ei + nb + 4);
            int4 ta = *(const int4*)(ei + NE + nb);
            int4 tb = *(const int4*)(ei + NE + nb + 4);
            ns[0]=rfl(sa.x); ns[1]=rfl(sa.y); ns[2]=rfl(sa.z); ns[3]=rfl(sa.w);
            ns[4]=rfl(sb.x); ns[5]=rfl(sb.y); ns[6]=rfl(sb.z); ns[7]=rfl(sb.w);
            nt[0]=rfl(ta.x); nt[1]=rfl(ta.y); nt[2]=rfl(ta.z); nt[3]=rfl(ta.w);
            nt[4]=rfl(tb.x); nt[5]=rfl(tb.y); nt[6]=rfl(tb.z); nt[7]=rfl(tb.w);
        }

        // (3) echo current ea rows straight from registers
        float4* ech = (float4*)(echo + (size_t)gb * 64);
        ech[lane] = A0;
        ech[64 + lane] = A1;

        // (4) register GEMM: acc[m] = (ea_row_m @ We^T + be)[lane]
        float acc[8];
#pragma unroll
        for (int m = 0; m < 8; m++) acc[m] = bias;
#pragma unroll
        for (int k = 0; k < 64; k++) {
            float w = WT[k * 65 + lane];
            const int ls = k >> 2, c = k & 3;
#pragma unroll
            for (int m = 0; m < 8; m++) {
                float comp = (m < 4)
                    ? (c == 0 ? A0.x : c == 1 ? A0.y : c == 2 ? A0.z : A0.w)
                    : (c == 0 ? A1.x : c == 1 ? A1.y : c == 2 ? A1.z : A1.w);
                float a = bcastf(comp, (m & 3) * 16 + ls);
                acc[m] = fmaf(a, w, acc[m]);
            }
        }

        // (5) epilogue: gathers have landed under the GEMM
#pragma unroll
        for (int m = 0; m < 8; m++) {
            float ev = acc[m];
            float z = kd[m] + qj[m] + ev + ev;          // (k_i+e) + (q_j+e)
            float g = 1.0f / (1.0f + __expf(-z));
            atomicAdd(&agg[(size_t)t[m] * 64 + lane], g * (vj[m] + ev));
        }

        if (!has_next) break;
        A0 = B0; A1 = B1;
#pragma unroll
        for (int m = 0; m < 8; m++) { s[m] = ns[m]; t[m] = nt[m]; }
        gb = nb;
    }
}

// ---------------------------------------------------------------------------
// final: out = relu(agg + x@Ws^T + bs); also echoes u and edge_index
// (folded in to drop the separate echo dispatch).
// ---------------------------------------------------------------------------
__global__ __launch_bounds__(256, 4) void final_kernel(
    const float* __restrict__ x, const float* __restrict__ Ws, const float* __restrict__ bs,
    const float* __restrict__ agg, const float* __restrict__ u,
    const int* __restrict__ ei, float* __restrict__ out)
{
    __shared__ float WT[64 * 65];
    const int tid = threadIdx.x;
    const int lane = tid & 63, wave = tid >> 6;

    // echo u (1024) + edge_index (2M ints -> floats), grid-stride
    {
        int gtid = blockIdx.x * 256 + tid;
        if (gtid < 1024) out[OUT_U + gtid] = u[gtid];
        for (int i = gtid; i < 2000000; i += 800000)
            out[OUT_EI + i] = (float)ei[i];
    }

    for (int i = tid; i < 64 * 64; i += 256) {
        int d = i >> 6, k = i & 63;
        WT[k * 65 + d] = Ws[i];
    }
    __syncthreads();

    const float bias = bs[lane];
    const int base = blockIdx.x * 32 + wave * 8;

    const float4* src = (const float4*)(x + (size_t)base * 64);
    float4 A0 = src[lane];
    float4 A1 = src[64 + lane];

    float acc[8];
#pragma unroll
    for (int m = 0; m < 8; m++) acc[m] = bias;

#pragma unroll
    for (int k = 0; k < 64; k++) {
        float w = WT[k * 65 + lane];
        const int ls = k >> 2, c = k & 3;
#pragma unroll
        for (int m = 0; m < 8; m++) {
            float comp = (m < 4)
                ? (c == 0 ? A0.x : c == 1 ? A0.y : c == 2 ? A0.z : A0.w)
                : (c == 0 ? A1.x : c == 1 ? A1.y : c == 2 ? A1.z : A1.w);
            float a = bcastf(comp, (m & 3) * 16 + ls);
            acc[m] = fmaf(a, w, acc[m]);
        }
    }

#pragma unroll
    for (int m = 0; m < 8; m++) {
        int row = base + m;
        float r = acc[m] + agg[(size_t)row * 64 + lane];
        out[(size_t)row * 64 + lane] = r > 0.0f ? r : 0.0f;
    }
}

extern "C" void kernel_launch(void* const* d_in, const int* in_sizes, int n_in,
                              void* d_out, int out_size, void* d_ws, size_t ws_size,
                              hipStream_t stream)
{
    const float* x  = (const float*)d_in[0];
    const int*   ei = (const int*)d_in[1];
    const float* ea = (const float*)d_in[2];
    const float* u  = (const float*)d_in[3];
    // d_in[4] = batch (unused by reference output)
    const float* Wk = (const float*)d_in[5];
    const float* bk = (const float*)d_in[6];
    const float* Wq = (const float*)d_in[7];
    const float* bq = (const float*)d_in[8];
    const float* Wv = (const float*)d_in[9];
    const float* bv = (const float*)d_in[10];
    const float* We = (const float*)d_in[11];
    const float* be = (const float*)d_in[12];
    const float* Ws = (const float*)d_in[13];
    const float* bs = (const float*)d_in[14];
    float* out = (float*)d_out;

    float* ws  = (float*)d_ws;
    float* ko  = ws;
    float* qo  = ws + 6400000;
    float* vo  = ws + 12800000;
    float* agg = ws + 19200000;

    proj_kernel <<<dim3(3125, 4), 256, 0, stream>>>(x, Wk, bk, Wq, bq, Wv, bv, ko, qo, vo, agg);
    edge_kernel <<<2048, 256, 0, stream>>>(ea, ei, We, be, ko, qo, vo, agg, out);
    final_kernel<<<3125, 256, 0, stream>>>(x, Ws, bs, agg, u, ei, out);
}